// Round 4
// baseline (503.051 us; speedup 1.0000x reference)
//
#include <hip/hip_runtime.h>
#include <hip/hip_bf16.h>

// Problem constants: B=2, L=2048, D=2048, H=16, Dh=128, 3D=6144
typedef unsigned short ushort_t;
typedef __attribute__((ext_vector_type(4))) float fvec4;
typedef __attribute__((ext_vector_type(16))) float fvec16;
typedef __attribute__((ext_vector_type(8))) short short8;   // 8 bf16 (4 VGPRs) - MFMA A/B frag
typedef __attribute__((ext_vector_type(4))) unsigned short usvec4;
typedef __attribute__((ext_vector_type(2))) unsigned int uvec2;

typedef const __attribute__((address_space(1))) void* gas_ptr;
typedef __attribute__((address_space(3))) void* las_ptr;

__device__ __forceinline__ void glds16(const void* g, void* l) {
  // async global->LDS, 16B/lane, LDS dest = wave-uniform base + lane*16
  __builtin_amdgcn_global_load_lds((gas_ptr)g, (las_ptr)l, 16, 0, 0);
}

__device__ __forceinline__ ushort_t f2bf(float f) {
  unsigned u = __float_as_uint(f);
  u += 0x7FFFu + ((u >> 16) & 1u);   // RNE
  return (ushort_t)(u >> 16);
}
__device__ __forceinline__ float bf2f(ushort_t h) {
  return __uint_as_float(((unsigned)h) << 16);
}

// permlane32_swap: a' = [a.lo32lanes, b.lo32lanes], b' = [a.hi, b.hi]
__device__ __forceinline__ void swap32(unsigned& a, unsigned& b) {
#if __has_builtin(__builtin_amdgcn_permlane32_swap)
  uvec2 r = __builtin_amdgcn_permlane32_swap(a, b, false, false);
  a = r[0]; b = r[1];
#else
  const unsigned sa = (unsigned)__shfl_xor((int)a, 32);
  const unsigned sb = (unsigned)__shfl_xor((int)b, 32);
  const bool hi = (threadIdx.x & 32) != 0;
  const unsigned na = hi ? sb : a;
  const unsigned nb = hi ? b : sa;
  a = na; b = nb;
#endif
}

// ---------------------------------------------------------------- cast x -> bf16
__global__ __launch_bounds__(256) void cast_f32_bf16(const float* __restrict__ X,
                                                     ushort_t* __restrict__ Xb) {
  const size_t i = ((size_t)blockIdx.x * 256 + threadIdx.x) * 4;
  const fvec4 v = *(const fvec4*)(X + i);
  usvec4 o;
  o[0] = f2bf(v[0]); o[1] = f2bf(v[1]); o[2] = f2bf(v[2]); o[3] = f2bf(v[3]);
  *(usvec4*)(Xb + i) = o;
}

// ------------------------------------- transpose+cast weights: W(Kd,Nd) -> Wt(Nd,Kd) bf16
__global__ __launch_bounds__(256) void tcast(const float* __restrict__ W,
                                             ushort_t* __restrict__ Wt,
                                             const int Kd, const int Nd) {
  __shared__ float ls[64][65];
  const int t = threadIdx.x;
  const int n0 = blockIdx.x * 64, k0 = blockIdx.y * 64;
  const int kr = t >> 4, nc = (t & 15) * 4;
#pragma unroll
  for (int it = 0; it < 4; ++it) {
    const fvec4 v = *(const fvec4*)(W + (size_t)(k0 + it * 16 + kr) * Nd + n0 + nc);
    ls[it * 16 + kr][nc + 0] = v[0];
    ls[it * 16 + kr][nc + 1] = v[1];
    ls[it * 16 + kr][nc + 2] = v[2];
    ls[it * 16 + kr][nc + 3] = v[3];
  }
  __syncthreads();
  const int nr = t >> 2, kg = (t & 3) * 16;
  __align__(16) ushort_t tmp[16];
#pragma unroll
  for (int i = 0; i < 16; ++i) tmp[i] = f2bf(ls[kg + i][nr]);
  ushort_t* dst = Wt + (size_t)(n0 + nr) * Kd + k0 + kg;
  *(short8*)(dst)     = *(const short8*)(tmp);
  *(short8*)(dst + 8) = *(const short8*)(tmp + 8);
}

// ---------------------------------------------------------------- bf16 GEMM, B^T input
// C(M,N) = A(M,K) * Bt(N,K)^T.  128x128 tile, BK=64, 4 waves (2x2 of 64x64),
// mfma_32x32x16 (half the MFMA issues of 16x16x32 for the same FLOPs; m119
// shows the 32x32 shape has the higher ceiling).
// XCD-band swizzle: bid%8 (heuristic XCD id) owns a contiguous band of ncx/8
// column-blocks, row-major within the band -> per-XCD B working set = ncx/8 *
// 0.5 MB (3 MB for QKV: fits the 4 MB private L2); A (16 MB) lives in L3.
// LDS fragment-ordered: frag f = wrm*4+kc (wrm = 32-row group, kc = K-group of
// 16), 512 ushorts per frag, lane slot = lane*8 (matches glds16 lane order:
// lane -> A[m=lane&31][k=kc*16+(lane>>5)*8 ..+7]).
// mode 0: fp32 C.  mode 1: scatter bf16 into Q/K/V (B,H,L,Dh); BN=128==Dh so
//         one block column == one head exactly.
__global__ __launch_bounds__(256) void gemm_bt(
    const ushort_t* __restrict__ A, const ushort_t* __restrict__ Bt,
    const int M, const int N, const int K, const int mode,
    float* __restrict__ C,
    ushort_t* __restrict__ Qo, ushort_t* __restrict__ Ko, ushort_t* __restrict__ Vo) {
  __shared__ __align__(16) ushort_t lA[8192];
  __shared__ __align__(16) ushort_t lB[8192];
  const int tid = threadIdx.x, wv = tid >> 6, lane = tid & 63;
  const int cq = lane & 31, lh = lane >> 5;
  // XCD-band swizzle (locality heuristic only — correctness-independent)
  const int ncx = gridDim.x;               // col-blocks, multiple of 8
  const int nbp = ncx >> 3;                // cols per XCD band
  const int bid = blockIdx.y * ncx + blockIdx.x;
  const int xcd = bid & 7, lid = bid >> 3;
  const int colb = xcd * nbp + (lid % nbp);
  const int rowb = lid / nbp;
  const int row0 = rowb * 128, col0 = colb * 128;
  const int wr = wv >> 1, wc = wv & 1;

  fvec16 acc[2][2];
#pragma unroll
  for (int i = 0; i < 2; ++i)
#pragma unroll
    for (int j = 0; j < 2; ++j)
#pragma unroll
      for (int r = 0; r < 16; ++r) acc[i][j][r] = 0.f;

  for (int k0 = 0; k0 < K; k0 += 64) {
    __syncthreads();
#pragma unroll
    for (int it = 0; it < 4; ++it) {
      const int f = it * 4 + wv;          // frag id, wave-uniform
      const int wrm = f >> 2, kc = f & 3;
      const ushort_t* ga = A + (size_t)(row0 + wrm * 32 + cq) * K + k0 + kc * 16 + lh * 8;
      glds16(ga, lA + f * 512);
      const ushort_t* gb = Bt + (size_t)(col0 + wrm * 32 + cq) * K + k0 + kc * 16 + lh * 8;
      glds16(gb, lB + f * 512);
    }
    __syncthreads();
#pragma unroll
    for (int kc = 0; kc < 4; ++kc) {
      short8 a0 = *(const short8*)(lA + ((wr * 2 + 0) * 4 + kc) * 512 + lane * 8);
      short8 a1 = *(const short8*)(lA + ((wr * 2 + 1) * 4 + kc) * 512 + lane * 8);
      short8 b0 = *(const short8*)(lB + ((wc * 2 + 0) * 4 + kc) * 512 + lane * 8);
      short8 b1 = *(const short8*)(lB + ((wc * 2 + 1) * 4 + kc) * 512 + lane * 8);
      acc[0][0] = __builtin_amdgcn_mfma_f32_32x32x16_bf16(a0, b0, acc[0][0], 0, 0, 0);
      acc[0][1] = __builtin_amdgcn_mfma_f32_32x32x16_bf16(a0, b1, acc[0][1], 0, 0, 0);
      acc[1][0] = __builtin_amdgcn_mfma_f32_32x32x16_bf16(a1, b0, acc[1][0], 0, 0, 0);
      acc[1][1] = __builtin_amdgcn_mfma_f32_32x32x16_bf16(a1, b1, acc[1][1], 0, 0, 0);
    }
  }

  // C/D 32x32 layout: col = lane&31, row = (r&3) + 8*(r>>2) + 4*(lane>>5)
  if (mode == 0) {
#pragma unroll
    for (int i = 0; i < 2; ++i)
#pragma unroll
      for (int j = 0; j < 2; ++j)
#pragma unroll
        for (int r = 0; r < 16; ++r) {
          const int row = row0 + wr * 64 + i * 32 + (r & 3) + 8 * (r >> 2) + 4 * lh;
          const int col = col0 + wc * 64 + j * 32 + cq;
          C[(size_t)row * N + col] = acc[i][j][r];
        }
  } else {
    const int which = col0 >> 11;            // 0:q 1:k 2:v
    const int h = (col0 >> 7) & 15;
    ushort_t* dst = (which == 0) ? Qo : (which == 1) ? Ko : Vo;
#pragma unroll
    for (int i = 0; i < 2; ++i)
#pragma unroll
      for (int j = 0; j < 2; ++j)
#pragma unroll
        for (int r = 0; r < 16; ++r) {
          const int row = row0 + wr * 64 + i * 32 + (r & 3) + 8 * (r >> 2) + 4 * lh;
          const int bb = row >> 11, l = row & 2047;
          const int dcol = wc * 64 + j * 32 + cq;
          dst[((size_t)(bb * 16 + h) * 2048 + l) * 128 + dcol] = f2bf(acc[i][j][r]);
        }
  }
}

// ---------------------------------------------------------------- RoPE in-place on Q,K
// (B,H,L,Dh) bf16; pairs (d, d+64) share angle = l * 10000^(-d/64).
// blockIdx.y: 0 -> Q (also folds in softmax scale 1/sqrt(Dh)), 1 -> K.
// Explicit range reduction to one revolution BEFORE __sincosf (HW sincos domain).
__global__ __launch_bounds__(256) void rope_kernel(ushort_t* Qb, ushort_t* Kb) {
  const int gid = blockIdx.x * 256 + threadIdx.x;
  const int pd = gid & 63;
  const int row = gid >> 6;      // b*H*L + h*L + l
  const int l = row & 2047;
  ushort_t* base = (blockIdx.y ? Kb : Qb) + (size_t)row * 128;
  const float a = bf2f(base[pd]);
  const float bv = bf2f(base[pd + 64]);
  const float invf_rev = exp2f(-(float)pd * 0.20762050593045702f) * 0.15915494309189535f;
  float rev = (float)l * invf_rev;
  rev -= floorf(rev);                         // [0,1)
  const float ang = rev * 6.283185307179586f;
  float s, c;
  __sincosf(ang, &s, &c);
  float na = a * c - bv * s;
  float nb = bv * c + a * s;
  if (blockIdx.y == 0) { na *= 0.08838834764831845f; nb *= 0.08838834764831845f; }
  base[pd] = f2bf(na);
  base[pd + 64] = f2bf(nb);
}

// ---------------------------------------------------------------- V transpose per head
// Vn (B,H,L,Dh) -> Vt (B,H,Dh,L)
__global__ __launch_bounds__(256) void vtrans_kernel(const ushort_t* __restrict__ Vn,
                                                     ushort_t* __restrict__ Vt) {
  __shared__ ushort_t ls[128 * 132];
  const int bh = blockIdx.x >> 4;
  const int l0 = (blockIdx.x & 15) * 128;
  const int t = threadIdx.x;
  const ushort_t* src = Vn + ((size_t)bh * 2048 + l0) * 128;
#pragma unroll
  for (int it = 0; it < 16; ++it) {
    const int c = it * 256 + t;
    const int lr = c >> 5, dc = (c & 31) * 4;
    *(usvec4*)(ls + lr * 132 + dc) = *(const usvec4*)(src + lr * 128 + dc);
  }
  __syncthreads();
  ushort_t* dstb = Vt + (size_t)bh * 128 * 2048 + l0;
#pragma unroll
  for (int it = 0; it < 16; ++it) {
    const int c = it * 256 + t;
    const int d = c >> 5, lc = (c & 31) * 4;
    usvec4 o;
    o[0] = ls[(lc + 0) * 132 + d];
    o[1] = ls[(lc + 1) * 132 + d];
    o[2] = ls[(lc + 2) * 132 + d];
    o[3] = ls[(lc + 3) * 132 + d];
    *(usvec4*)(dstb + (size_t)d * 2048 + lc) = o;
  }
}

// ---------------------------------------------------------------- flash attention v2
// Block = (b,h, q-tile of 128). 4 waves; wave owns 32 q-rows. K/V tiles of 64 keys.
// S^T = K·Q^T via mfma_32x32x16 (C-layout: col=q=lane&31, row=key) so the PV
// A-operand (m=q=lane&31) needs only cross-half key movement: cvt_pk_bf16 +
// v_permlane32_swap — NO LDS round-trip for P. Fixed-base softmax (scores are
// O(1) after 1/sqrt(Dh); exp(s) safe in fp32): no running max, no rescale;
// denominator = per-lane partials + one shfl_xor(32) at the end.
__global__ __launch_bounds__(256, 2) void flash_kernel(
    const ushort_t* __restrict__ Qb, const ushort_t* __restrict__ Kb,
    const ushort_t* __restrict__ Vt, const int* __restrict__ am,
    ushort_t* __restrict__ Y) {
  __shared__ __align__(16) ushort_t lK[8192];   // 16 frags (ct*8+c): K A-operand layout
  __shared__ __align__(16) ushort_t lV[8192];   // 16 frags (dt*4+kc): V B-operand layout
  __shared__ float lds_l[128];

  const int tid = threadIdx.x, wv = tid >> 6, lane = tid & 63;
  const int lh = lane >> 5, cq = lane & 31;
  const int bid = blockIdx.x;
  const int bh = bid & 31;                 // spread bh across consecutive blocks (XCDs)
  const int qi = 15 - (bid >> 5);          // biggest q-tiles dispatch first
  const int b = bh >> 4, head = bh & 15;
  const size_t qkBase = (size_t)bh * (2048 * 128);
  const int qb = qi * 128 + wv * 32;       // wave's first q row
  const int q = qb + cq;                   // this lane's q (S^T col / PV m)

  // Q B-frags: lane holds Q[q][c*16 + lh*8 + j]
  short8 qf[8];
  {
    const ushort_t* qrow = Qb + qkBase + (size_t)q * 128;
#pragma unroll
    for (int c = 0; c < 8; ++c) qf[c] = *(const short8*)(qrow + c * 16 + lh * 8);
  }

  fvec16 yacc[4];
#pragma unroll
  for (int i = 0; i < 4; ++i)
#pragma unroll
    for (int r = 0; r < 16; ++r) yacc[i][r] = 0.f;
  float psum = 0.f;

  const int nt = qi * 2 + 2;
  for (int t = 0; t < nt; ++t) {
    const int k0 = t * 64;
    __syncthreads();
#pragma unroll
    for (int it = 0; it < 4; ++it) {
      const int f = it * 4 + wv;           // frag id, wave-uniform
      { const int ct = f >> 3, c = f & 7;  // K frag: A[m=key(32)][k=dh(16)]
        const ushort_t* g = Kb + qkBase + (size_t)(k0 + ct * 32 + cq) * 128 + c * 16 + lh * 8;
        glds16(g, lK + f * 512); }
      { const int dt = f >> 2, kc = f & 3; // V frag: B[k=key(16)][n=d(32)]
        const ushort_t* g = Vt + ((size_t)bh * 128 + dt * 32 + cq) * 2048 + k0 + kc * 16 + lh * 8;
        glds16(g, lV + f * 512); }
    }
    __syncthreads();

    if (k0 > qb + 31) continue;            // tile fully causal-masked for this wave

    const int amv = am[b * 2048 + k0 + lane];
    const unsigned long long keymask = __ballot(amv != 0);
    const bool fullvalid = (k0 + 63 <= qb) && (keymask == ~0ull);

#pragma unroll
    for (int ct = 0; ct < 2; ++ct) {
      fvec16 sacc;
#pragma unroll
      for (int r = 0; r < 16; ++r) sacc[r] = 0.f;
#pragma unroll
      for (int c = 0; c < 8; ++c) {
        short8 kf = *(const short8*)(lK + (ct * 8 + c) * 512 + lane * 8);
        sacc = __builtin_amdgcn_mfma_f32_32x32x16_bf16(kf, qf[c], sacc, 0, 0, 0);
      }
      // S^T C-layout: value r is S[q][key] with key = (r&3)+8*(r>>2)+4*lh (+ct*32+k0)
      float p[16];
      if (fullvalid) {
#pragma unroll
        for (int r = 0; r < 16; ++r) p[r] = __expf(sacc[r]);
      } else {
#pragma unroll
        for (int r = 0; r < 16; ++r) {
          const int kl = (r & 3) + 8 * (r >> 2) + 4 * lh + ct * 32;
          const bool ok = (k0 + kl <= q) && (((keymask >> kl) & 1ull) != 0);
          p[r] = ok ? __expf(sacc[r]) : 0.f;
        }
      }
#pragma unroll
      for (int r = 0; r < 16; ++r) psum += p[r];
      // pack pairs of consecutive keys -> bf16x2
      unsigned pk[8];
#pragma unroll
      for (int j = 0; j < 8; ++j) {
        __hip_bfloat162 t2 = __float22bfloat162_rn(make_float2(p[2 * j], p[2 * j + 1]));
        pk[j] = *(unsigned*)&t2;           // low 16 bits = p[2j]
      }
      // permlane32_swap -> PV A-frags (keys cross the 32-lane halves; q stays put)
#pragma unroll
      for (int kc2 = 0; kc2 < 2; ++kc2) {
        unsigned a0 = pk[kc2 * 4 + 0], a2 = pk[kc2 * 4 + 2];
        unsigned a1 = pk[kc2 * 4 + 1], a3 = pk[kc2 * 4 + 3];
        swap32(a0, a2);
        swap32(a1, a3);
        union { unsigned u[4]; short8 s; } pf;
        pf.u[0] = a0; pf.u[1] = a1; pf.u[2] = a2; pf.u[3] = a3;
        const int kc = ct * 2 + kc2;
#pragma unroll
        for (int dt = 0; dt < 4; ++dt) {
          short8 vf = *(const short8*)(lV + (dt * 4 + kc) * 512 + lane * 8);
          yacc[dt] = __builtin_amdgcn_mfma_f32_32x32x16_bf16(pf.s, vf, yacc[dt], 0, 0, 0);
        }
      }
    }
  }

  // denominator: combine the two key-halves, publish per-q, build 1/l per C-row
  psum += __shfl_xor(psum, 32);
  if (lane < 32) lds_l[wv * 32 + lane] = psum;
  float inv16[16];
#pragma unroll
  for (int r = 0; r < 16; ++r)
    inv16[r] = 1.f / lds_l[wv * 32 + (r & 3) + 8 * (r >> 2) + 4 * lh];

#pragma unroll
  for (int dt = 0; dt < 4; ++dt)
#pragma unroll
    for (int r = 0; r < 16; ++r) {
      const int qloc = (r & 3) + 8 * (r >> 2) + 4 * lh;
      ushort_t* dst = Y + ((size_t)(b * 2048 + qb + qloc)) * 2048 + head * 128 + dt * 32 + cq;
      *dst = f2bf(yacc[dt][r] * inv16[r]);
    }
}

// ---------------------------------------------------------------- launch
extern "C" void kernel_launch(void* const* d_in, const int* in_sizes, int n_in,
                              void* d_out, int out_size, void* d_ws, size_t ws_size,
                              hipStream_t stream) {
  const float* x      = (const float*)d_in[0];
  const int*   amask  = (const int*)d_in[1];
  const float* w_qkv  = (const float*)d_in[2];
  const float* w_proj = (const float*)d_in[3];

  // workspace layout (elements of bf16); Yb aliases xb, Vt aliases wqkvT
  ushort_t* xb     = (ushort_t*)d_ws;          // 8,388,608   (dead after gemm1)
  ushort_t* wqkvT  = xb + 8388608;             // 12,582,912  (dead after gemm1)
  ushort_t* wprojT = wqkvT + 12582912;         // 4,194,304
  ushort_t* Qb     = wprojT + 4194304;         // 8,388,608
  ushort_t* Kb     = Qb + 8388608;             // 8,388,608
  ushort_t* Vn     = Kb + 8388608;             // 8,388,608  -> total 96 MiB
  ushort_t* Vt     = wqkvT;                    // reuse
  ushort_t* Yb     = xb;                       // reuse

  cast_f32_bf16<<<8192, 256, 0, stream>>>(x, xb);
  tcast<<<dim3(96, 32), 256, 0, stream>>>(w_qkv, wqkvT, 2048, 6144);
  tcast<<<dim3(32, 32), 256, 0, stream>>>(w_proj, wprojT, 2048, 2048);
  gemm_bt<<<dim3(48, 32), 256, 0, stream>>>(xb, wqkvT, 4096, 6144, 2048, 1,
                                            nullptr, Qb, Kb, Vn);
  rope_kernel<<<dim3(16384, 2), 256, 0, stream>>>(Qb, Kb);
  vtrans_kernel<<<512, 256, 0, stream>>>(Vn, Vt);
  flash_kernel<<<512, 256, 0, stream>>>(Qb, Kb, Vt, amask, Yb);
  gemm_bt<<<dim3(16, 32), 256, 0, stream>>>(Yb, wprojT, 4096, 2048, 2048, 0,
                                            (float*)d_out, nullptr, nullptr, nullptr);
}